// Round 1
// baseline (448.499 us; speedup 1.0000x reference)
//
#include <hip/hip_runtime.h>

#define B_  2
#define S_  512
#define E2_ 512
#define E_  256

#define TT  128   // t-tile per block (stage1)
#define KB  32    // k-tile per step
#define LDK 40    // padded LDS stride (elements)

using f32x4  = __attribute__((ext_vector_type(4))) float;
using bf16x8 = __attribute__((ext_vector_type(8))) short;

__device__ __forceinline__ unsigned short f2bf(float f) {
    unsigned u = __float_as_uint(f);
    unsigned r = (u + 0x7FFFu + ((u >> 16) & 1u)) >> 16;
    return (unsigned short)r;
}
__device__ __forceinline__ float bf2f(unsigned short h) {
    return __uint_as_float(((unsigned)h) << 16);
}
__device__ __forceinline__ float tanh_fast(float x) {
    // NaN-safe: e->inf gives 1-0=1 ; e->0 gives 1-2=-1
    float e = __expf(2.0f * x);
    return 1.0f - 2.0f / (e + 1.0f);
}

// ---------------- prep: Wd [E2][E] f32 -> WdT hi/lo [E][E2] bf16 ----------------
__global__ void prep_wdt(const float* __restrict__ Wd,
                         unsigned short* __restrict__ WdT_hi,
                         unsigned short* __restrict__ WdT_lo) {
    int idx = blockIdx.x * 256 + threadIdx.x;   // 0 .. 131071
    int h = idx >> 8;      // 0..511
    int d = idx & 255;     // 0..255
    float w = Wd[idx];     // Wd[h][d]
    unsigned short hi = f2bf(w);
    float lo = w - bf2f(hi);
    WdT_hi[d * E2_ + h] = hi;
    WdT_lo[d * E2_ + h] = f2bf(lo);
}

// ---------------- stage1: logits[b,s,t] -----------------------------------------
__global__ __launch_bounds__(512)
void stage1(const float* __restrict__ q,
            const unsigned short* __restrict__ WdT_hi,
            const unsigned short* __restrict__ WdT_lo,
            const float* __restrict__ vd,
            float* __restrict__ logits /* [B*S, S] */) {
    __shared__ unsigned short sA_hi[TT * LDK];
    __shared__ unsigned short sA_lo[TT * LDK];
    __shared__ unsigned short sB_hi[E_ * LDK];
    __shared__ unsigned short sB_lo[E_ * LDK];
    __shared__ float sQs[E2_];
    __shared__ float sVd[E_];
    __shared__ float sRed[TT * 4];

    const int tid = threadIdx.x;
    const int t0  = blockIdx.x * TT;
    const int s   = blockIdx.y;
    const int b   = blockIdx.z;

    sQs[tid] = q[((size_t)(b * S_ + s)) * E2_ + tid];
    if (tid < E_) sVd[tid] = vd[tid];
    __syncthreads();

    const int wave = tid >> 6;
    const int lane = tid & 63;
    const int wt   = wave >> 2;   // 0..1  : t-half
    const int wd   = wave & 3;    // 0..3  : d-quarter
    const int l15  = lane & 15;
    const int l4   = lane >> 4;   // 0..3

    f32x4 acc[4][4] = {};

    for (int ko = 0; ko < E2_ / KB; ++ko) {
        const int k0 = ko * KB;
        // ---- stage A: C[tl][kl] = q[b][t0+tl][k0+kl] * qs[k0+kl], hi/lo split
        {
            int tl = tid >> 2;            // 0..127
            int kl = (tid & 3) * 8;       // 0,8,16,24
            const float* gp = q + ((size_t)(b * S_ + t0 + tl)) * E2_ + k0 + kl;
            float4 v0 = *(const float4*)gp;
            float4 v1 = *(const float4*)(gp + 4);
            float pv[8] = {v0.x, v0.y, v0.z, v0.w, v1.x, v1.y, v1.z, v1.w};
#pragma unroll
            for (int j = 0; j < 8; ++j) {
                float p = pv[j] * sQs[k0 + kl + j];
                unsigned short hi = f2bf(p);
                float lo = p - bf2f(hi);
                sA_hi[tl * LDK + kl + j] = hi;
                sA_lo[tl * LDK + kl + j] = f2bf(lo);
            }
        }
        // ---- stage B: sB[d][kl] = WdT[d][k0+kl]  (256 x 32, hi & lo)
        {
            int dl = tid >> 1;            // 0..255
            int kl = (tid & 1) * 16;      // 0 or 16
            const unsigned short* gh = WdT_hi + (size_t)dl * E2_ + k0 + kl;
            const unsigned short* gl = WdT_lo + (size_t)dl * E2_ + k0 + kl;
            *(int4*)&sB_hi[dl * LDK + kl]     = *(const int4*)gh;
            *(int4*)&sB_hi[dl * LDK + kl + 8] = *(const int4*)(gh + 8);
            *(int4*)&sB_lo[dl * LDK + kl]     = *(const int4*)gl;
            *(int4*)&sB_lo[dl * LDK + kl + 8] = *(const int4*)(gl + 8);
        }
        __syncthreads();

        // ---- fragments + MFMA
        bf16x8 a_hi[4], a_lo[4], b_hi[4], b_lo[4];
#pragma unroll
        for (int ft = 0; ft < 4; ++ft) {
            int row = wt * 64 + ft * 16 + l15;
            int off = row * LDK + l4 * 8;
            a_hi[ft] = *(const bf16x8*)&sA_hi[off];
            a_lo[ft] = *(const bf16x8*)&sA_lo[off];
        }
#pragma unroll
        for (int fd = 0; fd < 4; ++fd) {
            int drow = wd * 64 + fd * 16 + l15;
            int off  = drow * LDK + l4 * 8;
            b_hi[fd] = *(const bf16x8*)&sB_hi[off];
            b_lo[fd] = *(const bf16x8*)&sB_lo[off];
        }
#pragma unroll
        for (int ft = 0; ft < 4; ++ft) {
#pragma unroll
            for (int fd = 0; fd < 4; ++fd) {
                acc[ft][fd] = __builtin_amdgcn_mfma_f32_16x16x32_bf16(a_hi[ft], b_hi[fd], acc[ft][fd], 0, 0, 0);
                acc[ft][fd] = __builtin_amdgcn_mfma_f32_16x16x32_bf16(a_hi[ft], b_lo[fd], acc[ft][fd], 0, 0, 0);
                acc[ft][fd] = __builtin_amdgcn_mfma_f32_16x16x32_bf16(a_lo[ft], b_hi[fd], acc[ft][fd], 0, 0, 0);
            }
        }
        __syncthreads();
    }

    // ---- epilogue: tanh, *vd, reduce over d
#pragma unroll
    for (int ft = 0; ft < 4; ++ft) {
#pragma unroll
        for (int r = 0; r < 4; ++r) {
            float p = 0.f;
#pragma unroll
            for (int fd = 0; fd < 4; ++fd) {
                int d = wd * 64 + fd * 16 + l15;
                p += tanh_fast(acc[ft][fd][r]) * sVd[d];
            }
            p += __shfl_xor(p, 1);
            p += __shfl_xor(p, 2);
            p += __shfl_xor(p, 4);
            p += __shfl_xor(p, 8);
            if (l15 == 0) {
                int tl = wt * 64 + ft * 16 + l4 * 4 + r;
                sRed[tl * 4 + wd] = p;
            }
        }
    }
    __syncthreads();
    if (tid < TT) {
        float v = sRed[tid * 4 + 0] + sRed[tid * 4 + 1] + sRed[tid * 4 + 2] + sRed[tid * 4 + 3];
        logits[((size_t)(b * S_ + s)) * S_ + t0 + tid] = v;
    }
}

// ---------------- softmax in place over rows of 512 ------------------------------
__global__ void softmax_k(float* __restrict__ atten) {
    const int row  = blockIdx.x;          // 0..1023
    const int lane = threadIdx.x;         // 64 threads
    float* p = atten + (size_t)row * S_;
    float4 v0 = *(float4*)(p + lane * 8);
    float4 v1 = *(float4*)(p + lane * 8 + 4);
    float vv[8] = {v0.x, v0.y, v0.z, v0.w, v1.x, v1.y, v1.z, v1.w};
    float m = vv[0];
#pragma unroll
    for (int j = 1; j < 8; ++j) m = fmaxf(m, vv[j]);
#pragma unroll
    for (int off = 1; off < 64; off <<= 1) m = fmaxf(m, __shfl_xor(m, off));
    float ssum = 0.f;
#pragma unroll
    for (int j = 0; j < 8; ++j) { vv[j] = __expf(vv[j] - m); ssum += vv[j]; }
#pragma unroll
    for (int off = 1; off < 64; off <<= 1) ssum += __shfl_xor(ssum, off);
    float inv = 1.0f / ssum;
    float4 o0 = {vv[0] * inv, vv[1] * inv, vv[2] * inv, vv[3] * inv};
    float4 o1 = {vv[4] * inv, vv[5] * inv, vv[6] * inv, vv[7] * inv};
    *(float4*)(p + lane * 8)     = o0;
    *(float4*)(p + lane * 8 + 4) = o1;
}

// ---------------- context = atten @ value (f32 tiled) -----------------------------
__global__ __launch_bounds__(256)
void context_k(const float* __restrict__ atten, const float* __restrict__ value,
               float* __restrict__ ctx) {
    __shared__ float sA[32][65];
    __shared__ float sV[64][65];
    const int b  = blockIdx.z;
    const int s0 = blockIdx.y * 32;
    const int e0 = blockIdx.x * 64;
    const int tid = threadIdx.x;
    const int ts = tid >> 4;      // 0..15 -> 2 s-rows each
    const int te = tid & 15;      // 0..15 -> 4 e-cols each

    float acc[2][4] = {};
    for (int k0 = 0; k0 < S_; k0 += 64) {
        {
            int r = tid >> 3;             // 0..31
            int c = (tid & 7) * 8;        // 0..56
            const float* ga = atten + ((size_t)(b * S_ + s0 + r)) * S_ + k0 + c;
            *(float4*)&sA[r][c]     = *(const float4*)ga;
            *(float4*)&sA[r][c + 4] = *(const float4*)(ga + 4);
        }
        {
            int r = tid >> 2;             // 0..63
            int c = (tid & 3) * 16;       // 0..48
            const float* gv = value + ((size_t)(b * S_ + k0 + r)) * E2_ + e0 + c;
#pragma unroll
            for (int j = 0; j < 16; j += 4)
                *(float4*)&sV[r][c + j] = *(const float4*)(gv + j);
        }
        __syncthreads();
#pragma unroll 8
        for (int kk = 0; kk < 64; ++kk) {
            float a0 = sA[ts * 2 + 0][kk];
            float a1 = sA[ts * 2 + 1][kk];
#pragma unroll
            for (int j = 0; j < 4; ++j) {
                float vvv = sV[kk][te * 4 + j];
                acc[0][j] += a0 * vvv;
                acc[1][j] += a1 * vvv;
            }
        }
        __syncthreads();
    }
#pragma unroll
    for (int i = 0; i < 2; ++i)
#pragma unroll
        for (int j = 0; j < 4; ++j)
            ctx[((size_t)(b * S_ + s0 + ts * 2 + i)) * E2_ + e0 + te * 4 + j] = acc[i][j];
}

extern "C" void kernel_launch(void* const* d_in, const int* in_sizes, int n_in,
                              void* d_out, int out_size, void* d_ws, size_t ws_size,
                              hipStream_t stream) {
    const float* query = (const float*)d_in[0];
    const float* value = (const float*)d_in[1];
    const float* Wd    = (const float*)d_in[2];
    const float* vd    = (const float*)d_in[3];

    float* out   = (float*)d_out;
    float* ctx   = out;                          // [B,S,E2] = 524288 f32
    float* atten = out + (size_t)B_ * S_ * E2_;  // [B,S,S]  = 524288 f32

    // WdT hi/lo bf16 splits: 2 * 256*512*2B = 512 KiB
    const size_t wdt_bytes = (size_t)2 * E_ * E2_ * sizeof(unsigned short);
    unsigned short* wdt_hi;
    if (ws_size >= wdt_bytes) {
        wdt_hi = (unsigned short*)d_ws;
    } else {
        // stash in the context region of d_out; context_k overwrites it at the end
        wdt_hi = (unsigned short*)ctx;
    }
    unsigned short* wdt_lo = wdt_hi + (size_t)E_ * E2_;

    prep_wdt<<<dim3(512), dim3(256), 0, stream>>>(Wd, wdt_hi, wdt_lo);
    stage1<<<dim3(S_ / TT, S_, B_), dim3(512), 0, stream>>>(query, wdt_hi, wdt_lo, vd, atten);
    softmax_k<<<dim3(B_ * S_), dim3(64), 0, stream>>>(atten);
    context_k<<<dim3(E2_ / 64, S_ / 32, B_), dim3(256), 0, stream>>>(atten, value, ctx);
}

// Round 2
// 428.839 us; speedup vs baseline: 1.0458x; 1.0458x over previous
//
#include <hip/hip_runtime.h>

#define B_  2
#define S_  512
#define E2_ 512
#define E_  256

#define TT  128   // t-tile per block (stage1)
#define KB  32    // k-tile per step

using f32x4  = __attribute__((ext_vector_type(4))) float;
using bf16x8 = __attribute__((ext_vector_type(8))) short;

__device__ __forceinline__ unsigned short f2bf(float f) {
    unsigned u = __float_as_uint(f);
    unsigned r = (u + 0x7FFFu + ((u >> 16) & 1u)) >> 16;
    return (unsigned short)r;
}
__device__ __forceinline__ float bf2f(unsigned short h) {
    return __uint_as_float(((unsigned)h) << 16);
}
__device__ __forceinline__ float tanh_fast(float x) {
    // NaN-safe: e->inf gives 1-0=1 ; e->0 gives 1-2=-1
    float e = __expf(2.0f * x);
    return 1.0f - 2.0f / (e + 1.0f);
}

// ---------------- prep: Wd [E2][E] f32 -> WdT hi/lo [E][E2] bf16 ----------------
__global__ void prep_wdt(const float* __restrict__ Wd,
                         unsigned short* __restrict__ WdT_hi,
                         unsigned short* __restrict__ WdT_lo) {
    int idx = blockIdx.x * 256 + threadIdx.x;   // 0 .. 131071
    int h = idx >> 8;      // 0..511
    int d = idx & 255;     // 0..255
    float w = Wd[idx];     // Wd[h][d]
    unsigned short hi = f2bf(w);
    float lo = w - bf2f(hi);
    WdT_hi[d * E2_ + h] = hi;
    WdT_lo[d * E2_ + h] = f2bf(lo);
}

// ---------------- stage1: logits[b,s,t] (upper-triangle blocks + mirror) ---------
__global__ __launch_bounds__(512)
void stage1(const float* __restrict__ q,
            const unsigned short* __restrict__ WdT_hi,
            const unsigned short* __restrict__ WdT_lo,
            const float* __restrict__ vd,
            float* __restrict__ logits /* [B*S, S] */) {
    const int ti = blockIdx.x;
    const int s  = blockIdx.y;
    const int b  = blockIdx.z;
    // symmetry: only compute t-tiles at or below s's tile; mirror-write the rest
    if (ti > (s >> 7)) return;

    // swizzled LDS tiles: element (row, k) at short-index row*32 + ((k>>3)^((row>>2)&3))*8 + (k&7)
    __shared__ unsigned short sA_hi[TT * KB];
    __shared__ unsigned short sA_lo[TT * KB];
    __shared__ unsigned short sB_hi[E_ * KB];
    __shared__ unsigned short sB_lo[E_ * KB];
    __shared__ float sQs[E2_];
    __shared__ float sVd[E_];

    const int tid = threadIdx.x;
    const int t0  = ti * TT;

    sQs[tid] = q[((size_t)(b * S_ + s)) * E2_ + tid];
    if (tid < E_) sVd[tid] = vd[tid];
    __syncthreads();

    const int wave = tid >> 6;
    const int lane = tid & 63;
    const int wt   = wave >> 2;   // 0..1  : t-half
    const int wd   = wave & 3;    // 0..3  : d-quarter
    const int l15  = lane & 15;
    const int l4   = lane >> 4;   // 0..3

    // staging indices (hoisted)
    const int a_tl = tid >> 2;          // 0..127
    const int a_g  = tid & 3;           // k-granule 0..3
    const int a_off = a_tl * KB + ((a_g ^ ((a_tl >> 2) & 3)) << 3);
    const float* a_gp = q + ((size_t)(b * S_ + t0 + a_tl)) * E2_ + a_g * 8;

    const int b_dl   = tid >> 1;        // 0..255
    const int b_half = tid & 1;         // 0..1
    const int b_sw   = (b_dl >> 2) & 3;
    const int b_off0 = b_dl * KB + (((2 * b_half)     ^ b_sw) << 3);
    const int b_off1 = b_dl * KB + (((2 * b_half + 1) ^ b_sw) << 3);
    const unsigned short* b_gh = WdT_hi + (size_t)b_dl * E2_ + b_half * 16;
    const unsigned short* b_gl = WdT_lo + (size_t)b_dl * E2_ + b_half * 16;

    f32x4 acc[4][4] = {};

    for (int ko = 0; ko < E2_ / KB; ++ko) {
        const int k0 = ko * KB;
        // ---- stage A: C[tl][k] = q[b][t0+tl][k0+k] * qs[k0+k], hi/lo split, packed b128
        {
            float4 v0 = *(const float4*)(a_gp + k0);
            float4 v1 = *(const float4*)(a_gp + k0 + 4);
            float pv[8] = {v0.x, v0.y, v0.z, v0.w, v1.x, v1.y, v1.z, v1.w};
            bf16x8 hv, lv;
#pragma unroll
            for (int j = 0; j < 8; ++j) {
                float p = pv[j] * sQs[k0 + a_g * 8 + j];
                unsigned short hi = f2bf(p);
                float lo = p - bf2f(hi);
                hv[j] = (short)hi;
                lv[j] = (short)f2bf(lo);
            }
            *(bf16x8*)&sA_hi[a_off] = hv;
            *(bf16x8*)&sA_lo[a_off] = lv;
        }
        // ---- stage B: sB[d][k] = WdT[d][k0+k], hi & lo, b128 copies
        {
            *(int4*)&sB_hi[b_off0] = *(const int4*)(b_gh + k0);
            *(int4*)&sB_hi[b_off1] = *(const int4*)(b_gh + k0 + 8);
            *(int4*)&sB_lo[b_off0] = *(const int4*)(b_gl + k0);
            *(int4*)&sB_lo[b_off1] = *(const int4*)(b_gl + k0 + 8);
        }
        __syncthreads();

        // ---- fragments + MFMA
        bf16x8 a_hi[4], a_lo[4], b_hi[4], b_lo[4];
#pragma unroll
        for (int ft = 0; ft < 4; ++ft) {
            int row = wt * 64 + ft * 16 + l15;
            int off = row * KB + ((l4 ^ ((row >> 2) & 3)) << 3);
            a_hi[ft] = *(const bf16x8*)&sA_hi[off];
            a_lo[ft] = *(const bf16x8*)&sA_lo[off];
        }
#pragma unroll
        for (int fd = 0; fd < 4; ++fd) {
            int drow = wd * 64 + fd * 16 + l15;
            int off  = drow * KB + ((l4 ^ ((drow >> 2) & 3)) << 3);
            b_hi[fd] = *(const bf16x8*)&sB_hi[off];
            b_lo[fd] = *(const bf16x8*)&sB_lo[off];
        }
#pragma unroll
        for (int ft = 0; ft < 4; ++ft) {
#pragma unroll
            for (int fd = 0; fd < 4; ++fd) {
                acc[ft][fd] = __builtin_amdgcn_mfma_f32_16x16x32_bf16(a_hi[ft], b_hi[fd], acc[ft][fd], 0, 0, 0);
                acc[ft][fd] = __builtin_amdgcn_mfma_f32_16x16x32_bf16(a_hi[ft], b_lo[fd], acc[ft][fd], 0, 0, 0);
                acc[ft][fd] = __builtin_amdgcn_mfma_f32_16x16x32_bf16(a_lo[ft], b_hi[fd], acc[ft][fd], 0, 0, 0);
            }
        }
        __syncthreads();
    }

    // ---- epilogue: tanh, *vd, reduce over d  (sRed overlays sA_hi, safe after barrier)
    float* sRed = (float*)sA_hi;
#pragma unroll
    for (int ft = 0; ft < 4; ++ft) {
#pragma unroll
        for (int r = 0; r < 4; ++r) {
            float p = 0.f;
#pragma unroll
            for (int fd = 0; fd < 4; ++fd) {
                int d = wd * 64 + fd * 16 + l15;
                p += tanh_fast(acc[ft][fd][r]) * sVd[d];
            }
            p += __shfl_xor(p, 1);
            p += __shfl_xor(p, 2);
            p += __shfl_xor(p, 4);
            p += __shfl_xor(p, 8);
            if (l15 == 0) {
                int tl = wt * 64 + ft * 16 + l4 * 4 + r;
                sRed[tl * 4 + wd] = p;
            }
        }
    }
    __syncthreads();
    if (tid < TT) {
        float v = sRed[tid * 4 + 0] + sRed[tid * 4 + 1] + sRed[tid * 4 + 2] + sRed[tid * 4 + 3];
        int t = t0 + tid;
        logits[((size_t)(b * S_ + s)) * S_ + t] = v;   // direct
        logits[((size_t)(b * S_ + t)) * S_ + s] = v;   // mirror (bitwise-identical value)
    }
}

// ---------------- softmax in place over rows of 512 ------------------------------
__global__ void softmax_k(float* __restrict__ atten) {
    const int row  = blockIdx.x;          // 0..1023
    const int lane = threadIdx.x;         // 64 threads
    float* p = atten + (size_t)row * S_;
    float4 v0 = *(float4*)(p + lane * 8);
    float4 v1 = *(float4*)(p + lane * 8 + 4);
    float vv[8] = {v0.x, v0.y, v0.z, v0.w, v1.x, v1.y, v1.z, v1.w};
    float m = vv[0];
#pragma unroll
    for (int j = 1; j < 8; ++j) m = fmaxf(m, vv[j]);
#pragma unroll
    for (int off = 1; off < 64; off <<= 1) m = fmaxf(m, __shfl_xor(m, off));
    float ssum = 0.f;
#pragma unroll
    for (int j = 0; j < 8; ++j) { vv[j] = __expf(vv[j] - m); ssum += vv[j]; }
#pragma unroll
    for (int off = 1; off < 64; off <<= 1) ssum += __shfl_xor(ssum, off);
    float inv = 1.0f / ssum;
    float4 o0 = {vv[0] * inv, vv[1] * inv, vv[2] * inv, vv[3] * inv};
    float4 o1 = {vv[4] * inv, vv[5] * inv, vv[6] * inv, vv[7] * inv};
    *(float4*)(p + lane * 8)     = o0;
    *(float4*)(p + lane * 8 + 4) = o1;
}

// ---------------- context = atten @ value (f32 tiled) -----------------------------
__global__ __launch_bounds__(256)
void context_k(const float* __restrict__ atten, const float* __restrict__ value,
               float* __restrict__ ctx) {
    __shared__ float sA[32][65];
    __shared__ float sV[64][65];
    const int b  = blockIdx.z;
    const int s0 = blockIdx.y * 32;
    const int e0 = blockIdx.x * 64;
    const int tid = threadIdx.x;
    const int ts = tid >> 4;      // 0..15 -> 2 s-rows each
    const int te = tid & 15;      // 0..15 -> 4 e-cols each

    float acc[2][4] = {};
    for (int k0 = 0; k0 < S_; k0 += 64) {
        {
            int r = tid >> 3;             // 0..31
            int c = (tid & 7) * 8;        // 0..56
            const float* ga = atten + ((size_t)(b * S_ + s0 + r)) * S_ + k0 + c;
            *(float4*)&sA[r][c]     = *(const float4*)ga;
            *(float4*)&sA[r][c + 4] = *(const float4*)(ga + 4);
        }
        {
            int r = tid >> 2;             // 0..63
            int c = (tid & 3) * 16;       // 0..48
            const float* gv = value + ((size_t)(b * S_ + k0 + r)) * E2_ + e0 + c;
#pragma unroll
            for (int j = 0; j < 16; j += 4)
                *(float4*)&sV[r][c + j] = *(const float4*)(gv + j);
        }
        __syncthreads();
#pragma unroll 8
        for (int kk = 0; kk < 64; ++kk) {
            float a0 = sA[ts * 2 + 0][kk];
            float a1 = sA[ts * 2 + 1][kk];
#pragma unroll
            for (int j = 0; j < 4; ++j) {
                float vvv = sV[kk][te * 4 + j];
                acc[0][j] += a0 * vvv;
                acc[1][j] += a1 * vvv;
            }
        }
        __syncthreads();
    }
#pragma unroll
    for (int i = 0; i < 2; ++i)
#pragma unroll
        for (int j = 0; j < 4; ++j)
            ctx[((size_t)(b * S_ + s0 + ts * 2 + i)) * E2_ + e0 + te * 4 + j] = acc[i][j];
}

extern "C" void kernel_launch(void* const* d_in, const int* in_sizes, int n_in,
                              void* d_out, int out_size, void* d_ws, size_t ws_size,
                              hipStream_t stream) {
    const float* query = (const float*)d_in[0];
    const float* value = (const float*)d_in[1];
    const float* Wd    = (const float*)d_in[2];
    const float* vd    = (const float*)d_in[3];

    float* out   = (float*)d_out;
    float* ctx   = out;                          // [B,S,E2] = 524288 f32
    float* atten = out + (size_t)B_ * S_ * E2_;  // [B,S,S]  = 524288 f32

    // WdT hi/lo bf16 splits: 2 * 256*512*2B = 512 KiB
    const size_t wdt_bytes = (size_t)2 * E_ * E2_ * sizeof(unsigned short);
    unsigned short* wdt_hi;
    if (ws_size >= wdt_bytes) {
        wdt_hi = (unsigned short*)d_ws;
    } else {
        // stash in the context region of d_out; context_k overwrites it at the end
        wdt_hi = (unsigned short*)ctx;
    }
    unsigned short* wdt_lo = wdt_hi + (size_t)E_ * E2_;

    prep_wdt<<<dim3(512), dim3(256), 0, stream>>>(Wd, wdt_hi, wdt_lo);
    stage1<<<dim3(S_ / TT, S_, B_), dim3(512), 0, stream>>>(query, wdt_hi, wdt_lo, vd, atten);
    softmax_k<<<dim3(B_ * S_), dim3(64), 0, stream>>>(atten);
    context_k<<<dim3(E2_ / 64, S_ / 32, B_), dim3(256), 0, stream>>>(atten, value, ctx);
}

// Round 3
// 295.649 us; speedup vs baseline: 1.5170x; 1.4505x over previous
//
#include <hip/hip_runtime.h>

#define B_  2
#define S_  512
#define E2_ 512
#define E_  256

#define TT  128   // t-tile per block (stage1)
#define KB  32    // k-tile per step

using f32x4  = __attribute__((ext_vector_type(4))) float;
using bf16x8 = __attribute__((ext_vector_type(8))) short;

__device__ __forceinline__ unsigned short f2bf(float f) {
    unsigned u = __float_as_uint(f);
    unsigned r = (u + 0x7FFFu + ((u >> 16) & 1u)) >> 16;
    return (unsigned short)r;
}
__device__ __forceinline__ float bf2f(unsigned short h) {
    return __uint_as_float(((unsigned)h) << 16);
}
__device__ __forceinline__ float tanh_fast(float x) {
    // NaN-safe: e->inf gives 1-0=1 ; e->0 gives 1-2=-1
    float e = __expf(2.0f * x);
    return 1.0f - 2.0f / (e + 1.0f);
}

// ---------------- prep: Wd [E2][E] f32 -> WdT hi/lo [E][E2] bf16 ----------------
__global__ void prep_wdt(const float* __restrict__ Wd,
                         unsigned short* __restrict__ WdT_hi,
                         unsigned short* __restrict__ WdT_lo) {
    int idx = blockIdx.x * 256 + threadIdx.x;   // 0 .. 131071
    int h = idx >> 8;      // 0..511
    int d = idx & 255;     // 0..255
    float w = Wd[idx];     // Wd[h][d]
    unsigned short hi = f2bf(w);
    float lo = w - bf2f(hi);
    WdT_hi[d * E2_ + h] = hi;
    WdT_lo[d * E2_ + h] = f2bf(lo);
}

// ---------------- stage1: logits[b,s,t], dense triangular grid -------------------
// blockIdx.x in [0, 1280): p = x>>7 selects tile-pair (ti<=sj), sl = x&127 selects s
__global__ __launch_bounds__(512)
void stage1(const float* __restrict__ q,
            const unsigned short* __restrict__ WdT_hi,
            const unsigned short* __restrict__ WdT_lo,
            const float* __restrict__ vd,
            float* __restrict__ logits /* [B*S, S] */) {
    const int p  = blockIdx.x >> 7;    // 0..9 tile-pair
    const int sl = blockIdx.x & 127;
    const int b  = blockIdx.y;
    const int sj = (p >= 6) ? 3 : (p >= 3) ? 2 : (p >= 1) ? 1 : 0;
    const int ti = p - ((sj * (sj + 1)) >> 1);
    const int s  = sj * TT + sl;
    const int t0 = ti * TT;

    // swizzled LDS tiles: element (row, k) at short-index row*32 + ((k>>3)^((row>>2)&3))*8 + (k&7)
    __shared__ unsigned short sA_hi[TT * KB];
    __shared__ unsigned short sA_lo[TT * KB];
    __shared__ unsigned short sB_hi[E_ * KB];
    __shared__ unsigned short sB_lo[E_ * KB];
    __shared__ float sQs[E2_];
    __shared__ float sVd[E_];

    const int tid = threadIdx.x;

    sQs[tid] = q[((size_t)(b * S_ + s)) * E2_ + tid];
    if (tid < E_) sVd[tid] = vd[tid];
    __syncthreads();

    const int wave = tid >> 6;
    const int lane = tid & 63;
    const int wt   = wave >> 2;   // 0..1  : t-half
    const int wd   = wave & 3;    // 0..3  : d-quarter
    const int l15  = lane & 15;
    const int l4   = lane >> 4;   // 0..3

    // staging indices (hoisted)
    const int a_tl = tid >> 2;          // 0..127
    const int a_g  = tid & 3;           // k-granule 0..3
    const int a_off = a_tl * KB + ((a_g ^ ((a_tl >> 2) & 3)) << 3);
    const float* a_gp = q + ((size_t)(b * S_ + t0 + a_tl)) * E2_ + a_g * 8;

    const int b_dl   = tid >> 1;        // 0..255
    const int b_half = tid & 1;         // 0..1
    const int b_sw   = (b_dl >> 2) & 3;
    const int b_off0 = b_dl * KB + (((2 * b_half)     ^ b_sw) << 3);
    const int b_off1 = b_dl * KB + (((2 * b_half + 1) ^ b_sw) << 3);
    const unsigned short* b_gh = WdT_hi + (size_t)b_dl * E2_ + b_half * 16;
    const unsigned short* b_gl = WdT_lo + (size_t)b_dl * E2_ + b_half * 16;

    f32x4 acc[4][4] = {};

    for (int ko = 0; ko < E2_ / KB; ++ko) {
        const int k0 = ko * KB;
        // ---- stage A: C[tl][k] = q[b][t0+tl][k0+k] * qs[k0+k], hi/lo split, packed b128
        {
            float4 v0 = *(const float4*)(a_gp + k0);
            float4 v1 = *(const float4*)(a_gp + k0 + 4);
            float pv[8] = {v0.x, v0.y, v0.z, v0.w, v1.x, v1.y, v1.z, v1.w};
            bf16x8 hv, lv;
#pragma unroll
            for (int j = 0; j < 8; ++j) {
                float p2 = pv[j] * sQs[k0 + a_g * 8 + j];
                unsigned short hi = f2bf(p2);
                float lo = p2 - bf2f(hi);
                hv[j] = (short)hi;
                lv[j] = (short)f2bf(lo);
            }
            *(bf16x8*)&sA_hi[a_off] = hv;
            *(bf16x8*)&sA_lo[a_off] = lv;
        }
        // ---- stage B: sB[d][k] = WdT[d][k0+k], hi & lo, b128 copies
        {
            *(int4*)&sB_hi[b_off0] = *(const int4*)(b_gh + k0);
            *(int4*)&sB_hi[b_off1] = *(const int4*)(b_gh + k0 + 8);
            *(int4*)&sB_lo[b_off0] = *(const int4*)(b_gl + k0);
            *(int4*)&sB_lo[b_off1] = *(const int4*)(b_gl + k0 + 8);
        }
        __syncthreads();

        // ---- fragments + MFMA
        bf16x8 a_hi[4], a_lo[4], b_hi[4], b_lo[4];
#pragma unroll
        for (int ft = 0; ft < 4; ++ft) {
            int row = wt * 64 + ft * 16 + l15;
            int off = row * KB + ((l4 ^ ((row >> 2) & 3)) << 3);
            a_hi[ft] = *(const bf16x8*)&sA_hi[off];
            a_lo[ft] = *(const bf16x8*)&sA_lo[off];
        }
#pragma unroll
        for (int fd = 0; fd < 4; ++fd) {
            int drow = wd * 64 + fd * 16 + l15;
            int off  = drow * KB + ((l4 ^ ((drow >> 2) & 3)) << 3);
            b_hi[fd] = *(const bf16x8*)&sB_hi[off];
            b_lo[fd] = *(const bf16x8*)&sB_lo[off];
        }
#pragma unroll
        for (int ft = 0; ft < 4; ++ft) {
#pragma unroll
            for (int fd = 0; fd < 4; ++fd) {
                acc[ft][fd] = __builtin_amdgcn_mfma_f32_16x16x32_bf16(a_hi[ft], b_hi[fd], acc[ft][fd], 0, 0, 0);
                acc[ft][fd] = __builtin_amdgcn_mfma_f32_16x16x32_bf16(a_hi[ft], b_lo[fd], acc[ft][fd], 0, 0, 0);
                acc[ft][fd] = __builtin_amdgcn_mfma_f32_16x16x32_bf16(a_lo[ft], b_hi[fd], acc[ft][fd], 0, 0, 0);
            }
        }
        __syncthreads();
    }

    // ---- epilogue: tanh, *vd, reduce over d  (sRed overlays sA_hi, safe after barrier)
    float* sRed = (float*)sA_hi;
#pragma unroll
    for (int ft = 0; ft < 4; ++ft) {
#pragma unroll
        for (int r = 0; r < 4; ++r) {
            float pp = 0.f;
#pragma unroll
            for (int fd = 0; fd < 4; ++fd) {
                int d = wd * 64 + fd * 16 + l15;
                pp += tanh_fast(acc[ft][fd][r]) * sVd[d];
            }
            pp += __shfl_xor(pp, 1);
            pp += __shfl_xor(pp, 2);
            pp += __shfl_xor(pp, 4);
            pp += __shfl_xor(pp, 8);
            if (l15 == 0) {
                int tl = wt * 64 + ft * 16 + l4 * 4 + r;
                sRed[tl * 4 + wd] = pp;
            }
        }
    }
    __syncthreads();
    if (tid < TT) {
        float v = sRed[tid * 4 + 0] + sRed[tid * 4 + 1] + sRed[tid * 4 + 2] + sRed[tid * 4 + 3];
        int t = t0 + tid;
        logits[((size_t)(b * S_ + s)) * S_ + t] = v;   // direct
        logits[((size_t)(b * S_ + t)) * S_ + s] = v;   // mirror (bitwise-identical value)
    }
}

// ---------------- softmax in place over rows of 512 ------------------------------
__global__ void softmax_k(float* __restrict__ atten) {
    const int row  = blockIdx.x;          // 0..1023
    const int lane = threadIdx.x;         // 64 threads
    float* p = atten + (size_t)row * S_;
    float4 v0 = *(float4*)(p + lane * 8);
    float4 v1 = *(float4*)(p + lane * 8 + 4);
    float vv[8] = {v0.x, v0.y, v0.z, v0.w, v1.x, v1.y, v1.z, v1.w};
    float m = vv[0];
#pragma unroll
    for (int j = 1; j < 8; ++j) m = fmaxf(m, vv[j]);
#pragma unroll
    for (int off = 1; off < 64; off <<= 1) m = fmaxf(m, __shfl_xor(m, off));
    float ssum = 0.f;
#pragma unroll
    for (int j = 0; j < 8; ++j) { vv[j] = __expf(vv[j] - m); ssum += vv[j]; }
#pragma unroll
    for (int off = 1; off < 64; off <<= 1) ssum += __shfl_xor(ssum, off);
    float inv = 1.0f / ssum;
    float4 o0 = {vv[0] * inv, vv[1] * inv, vv[2] * inv, vv[3] * inv};
    float4 o1 = {vv[4] * inv, vv[5] * inv, vv[6] * inv, vv[7] * inv};
    *(float4*)(p + lane * 8)     = o0;
    *(float4*)(p + lane * 8 + 4) = o1;
}

// ---------------- context = atten @ value (f32 tiled) -----------------------------
__global__ __launch_bounds__(256)
void context_k(const float* __restrict__ atten, const float* __restrict__ value,
               float* __restrict__ ctx) {
    __shared__ float sA[32][65];
    __shared__ float sV[64][65];
    const int b  = blockIdx.z;
    const int s0 = blockIdx.y * 32;
    const int e0 = blockIdx.x * 64;
    const int tid = threadIdx.x;
    const int ts = tid >> 4;      // 0..15 -> 2 s-rows each
    const int te = tid & 15;      // 0..15 -> 4 e-cols each

    float acc[2][4] = {};
    for (int k0 = 0; k0 < S_; k0 += 64) {
        {
            int r = tid >> 3;             // 0..31
            int c = (tid & 7) * 8;        // 0..56
            const float* ga = atten + ((size_t)(b * S_ + s0 + r)) * S_ + k0 + c;
            *(float4*)&sA[r][c]     = *(const float4*)ga;
            *(float4*)&sA[r][c + 4] = *(const float4*)(ga + 4);
        }
        {
            int r = tid >> 2;             // 0..63
            int c = (tid & 3) * 16;       // 0..48
            const float* gv = value + ((size_t)(b * S_ + k0 + r)) * E2_ + e0 + c;
#pragma unroll
            for (int j = 0; j < 16; j += 4)
                *(float4*)&sV[r][c + j] = *(const float4*)(gv + j);
        }
        __syncthreads();
#pragma unroll 8
        for (int kk = 0; kk < 64; ++kk) {
            float a0 = sA[ts * 2 + 0][kk];
            float a1 = sA[ts * 2 + 1][kk];
#pragma unroll
            for (int j = 0; j < 4; ++j) {
                float vvv = sV[kk][te * 4 + j];
                acc[0][j] += a0 * vvv;
                acc[1][j] += a1 * vvv;
            }
        }
        __syncthreads();
    }
#pragma unroll
    for (int i = 0; i < 2; ++i)
#pragma unroll
        for (int j = 0; j < 4; ++j)
            ctx[((size_t)(b * S_ + s0 + ts * 2 + i)) * E2_ + e0 + te * 4 + j] = acc[i][j];
}

extern "C" void kernel_launch(void* const* d_in, const int* in_sizes, int n_in,
                              void* d_out, int out_size, void* d_ws, size_t ws_size,
                              hipStream_t stream) {
    const float* query = (const float*)d_in[0];
    const float* value = (const float*)d_in[1];
    const float* Wd    = (const float*)d_in[2];
    const float* vd    = (const float*)d_in[3];

    float* out   = (float*)d_out;
    float* ctx   = out;                          // [B,S,E2] = 524288 f32
    float* atten = out + (size_t)B_ * S_ * E2_;  // [B,S,S]  = 524288 f32

    // WdT hi/lo bf16 splits: 2 * 256*512*2B = 512 KiB
    const size_t wdt_bytes = (size_t)2 * E_ * E2_ * sizeof(unsigned short);
    unsigned short* wdt_hi;
    if (ws_size >= wdt_bytes) {
        wdt_hi = (unsigned short*)d_ws;
    } else {
        // stash in the context region of d_out; context_k overwrites it at the end
        wdt_hi = (unsigned short*)ctx;
    }
    unsigned short* wdt_lo = wdt_hi + (size_t)E_ * E2_;

    prep_wdt<<<dim3(512), dim3(256), 0, stream>>>(Wd, wdt_hi, wdt_lo);
    // dense triangular grid: 10 tile-pairs * 128 s-values = 1280 blocks per batch
    stage1<<<dim3(1280, B_), dim3(512), 0, stream>>>(query, wdt_hi, wdt_lo, vd, atten);
    softmax_k<<<dim3(B_ * S_), dim3(64), 0, stream>>>(atten);
    context_k<<<dim3(E2_ / 64, S_ / 32, B_), dim3(256), 0, stream>>>(atten, value, ctx);
}